// Round 14
// baseline (258.445 us; speedup 1.0000x reference)
//
#include <hip/hip_runtime.h>
#include <cstdint>
#include <cstring>

typedef unsigned short ushort_t;
typedef __attribute__((ext_vector_type(8))) short short8;
typedef __attribute__((ext_vector_type(4))) float f32x4;
typedef __attribute__((ext_vector_type(4))) unsigned short us4;

constexpr int Hh = 8;
constexpr int Ss = 1024;
constexpr int Ee = 512;

__device__ __forceinline__ ushort_t f2bf(float f) {
    uint32_t u; __builtin_memcpy(&u, &f, 4);
    u += 0x7fffu + ((u >> 16) & 1u);   // RNE
    return (ushort_t)(u >> 16);
}
__device__ __forceinline__ float bf2f(ushort_t h) {
    uint32_t u = ((uint32_t)h) << 16; float f; __builtin_memcpy(&f, &u, 4); return f;
}

__device__ __forceinline__ void gload_lds16(const ushort_t* g, void* lds) {
    __builtin_amdgcn_global_load_lds(
        (const __attribute__((address_space(1))) void*)g,
        (__attribute__((address_space(3))) void*)lds, 16, 0, 0);
}

// ---------------- small kernels ----------------

__global__ void cvt_f32_bf16(const float4* __restrict__ in, us4* __restrict__ out, int n4) {
    int i = blockIdx.x * blockDim.x + threadIdx.x;
    if (i < n4) {
        float4 v = in[i];
        us4 o = { f2bf(v.x), f2bf(v.y), f2bf(v.z), f2bf(v.w) };
        out[i] = o;
    }
}

// all three W (h,e,f) fp32 -> contiguous Wt (24 x 512 x 512) bf16; z = mat*8+h
__global__ void wtrans_all(const float* __restrict__ Wq, const float* __restrict__ Wk,
                           const float* __restrict__ Wv, ushort_t* __restrict__ Wt) {
    __shared__ float tile[32][33];
    int zz = blockIdx.z;
    int h = zz & 7, sel = zz >> 3;
    const float* W = (sel == 0 ? Wq : (sel == 1 ? Wk : Wv));
    int e0 = blockIdx.y * 32, f0 = blockIdx.x * 32;
    int tx = threadIdx.x, ty = threadIdx.y;
    #pragma unroll
    for (int i = 0; i < 4; i++) {
        int e = e0 + ty + i * 8;
        tile[ty + i * 8][tx] = W[((size_t)h * 512 + e) * 512 + f0 + tx];
    }
    __syncthreads();
    #pragma unroll
    for (int i = 0; i < 4; i++) {
        int f = f0 + ty + i * 8;
        Wt[((size_t)zz * 512 + f) * 512 + e0 + tx] = f2bf(tile[tx][ty + i * 8]);
    }
}

// row-wise sum of squares over 512 bf16 elems; one wave per row
__global__ void sumsq(const ushort_t* __restrict__ X, float* __restrict__ out) {
    int row = blockIdx.x * 4 + (threadIdx.x >> 6);
    int ln = threadIdx.x & 63;
    short8 v = *(const short8*)(X + (size_t)row * 512 + ln * 8);
    float s = 0.f;
    #pragma unroll
    for (int j = 0; j < 8; j++) {
        float f = bf2f((ushort_t)v[j]);
        s += f * f;
    }
    #pragma unroll
    for (int off = 32; off > 0; off >>= 1) s += __shfl_xor(s, off);
    if (ln == 0) out[row] = s;
}

// sum 2 fp32 partials -> out
__global__ void reduce2(const f32x4* __restrict__ p, f32x4* __restrict__ out, int n4) {
    int i = blockIdx.x * blockDim.x + threadIdx.x;
    if (i < n4) out[i] = p[i] + p[i + (size_t)n4];
}

// ---------------- merged QKV projection (R13 engine, EPI5 only) ----------------
__global__ __launch_bounds__(512, 1)
void g_proj(const ushort_t* __restrict__ A, int lda,
            const ushort_t* __restrict__ Bm, int ldb,
            void* __restrict__ Cout, int K,
            void* __restrict__ Cout2)
{
    __shared__ __align__(16) ushort_t SMEM[65536];   // 128 KB

    const int t  = threadIdx.x;
    const int wv = t >> 6, ln = t & 63;
    const int wm = wv >> 2, wn = wv & 3;

    const int gx = gridDim.x, gy = gridDim.y;
    const int gxy = gx * gy;
    const int L = blockIdx.x + gx * (blockIdx.y + gy * blockIdx.z);
    const int xcd = L & 7;
    const int j = L >> 3;
    const int z  = xcd + 8 * (j / gxy);
    const int rem = j % gxy;
    const int by = rem / gx;
    const int bx = rem % gx;

    const int m0 = by * 256, n0 = bx * 256;

    const ushort_t* Ab = A;
    const ushort_t* Bb = Bm + (size_t)z * Ee * Ee;

    f32x4 acc[8][4];
    #pragma unroll
    for (int i = 0; i < 8; i++)
        #pragma unroll
        for (int j2 = 0; j2 < 4; j2++) acc[i][j2] = (f32x4){0.f, 0.f, 0.f, 0.f};

    const int srow = ln >> 3;
    const int schk = ((ln & 7) ^ srow) * 8;
    const ushort_t* sbase[4][2];
    int ldso[4][2];
    #pragma unroll
    for (int kind = 0; kind < 4; ++kind) {
        #pragma unroll
        for (int c = 0; c < 2; ++c) {
            const int idx = (kind & 1) * 16 + wv * 2 + c;
            const int rb = idx * 8 + srow;
            sbase[kind][c] = (kind < 2)
                ? Ab + (size_t)(m0 + rb) * lda + schk
                : Bb + (size_t)(n0 + rb) * ldb + schk;
            ldso[kind][c] = (kind < 2 ? 0 : 32768) + idx * 512;
        }
    }
    auto STAGE_UNIT = [&](int tile, int kind) {
        const int k0 = tile << 6;
        const int par = (tile & 1) * 16384;
        #pragma unroll
        for (int c = 0; c < 2; ++c)
            gload_lds16(sbase[kind][c] + k0, &SMEM[ldso[kind][c] + par]);
    };

    const int T = K >> 6;

    #pragma unroll
    for (int kk = 0; kk < 4; ++kk) STAGE_UNIT(0, kk);
    #pragma unroll
    for (int kk = 0; kk < 4; ++kk) STAGE_UNIT(1, kk);
    asm volatile("s_waitcnt vmcnt(8)" ::: "memory");
    __builtin_amdgcn_s_barrier();

    const int lrow = ln & 15, lkg = ln >> 4;
    const int swz = lrow & 7;

    for (int u = 0; u < (T >> 1); ++u) {
        short8 bfr[4][2];
        #pragma unroll
        for (int p = 0; p < 8; ++p) {
            const int d = p >> 2, q = p & 3;

            if (q == 0) {
                #pragma unroll
                for (int fc = 0; fc < 4; fc++)
                    #pragma unroll
                    for (int kg = 0; kg < 2; kg++)
                        bfr[fc][kg] = *(const short8*)(&SMEM[32768 + d * 16384 +
                                          (wn * 64 + fc * 16 + lrow) * 64 +
                                          (((kg * 4 + lkg) ^ swz) << 3)]);
            }
            short8 af[2][2];
            #pragma unroll
            for (int j2 = 0; j2 < 2; j2++)
                #pragma unroll
                for (int kg = 0; kg < 2; kg++)
                    af[j2][kg] = *(const short8*)(&SMEM[d * 16384 +
                                     (wm * 128 + (q * 2 + j2) * 16 + lrow) * 64 +
                                     (((kg * 4 + lkg) ^ swz) << 3)]);

            {
                int stile, skind;
                if      (p == 0) { stile = 2 * u + 1; skind = 0; }
                else if (p == 1) { stile = 2 * u + 1; skind = 1; }
                else if (p == 2) { stile = 2 * u + 2; skind = 2; }
                else if (p == 3) { stile = 2 * u + 2; skind = 3; }
                else if (p == 4) { stile = 2 * u + 2; skind = 0; }
                else if (p == 5) { stile = 2 * u + 2; skind = 1; }
                else if (p == 6) { stile = 2 * u + 3; skind = 2; }
                else             { stile = 2 * u + 3; skind = 3; }
                if (stile < T && !(u == 0 && stile == 1))
                    STAGE_UNIT(stile, skind);
            }

            __builtin_amdgcn_s_barrier();

            __builtin_amdgcn_s_setprio(1);
            #pragma unroll
            for (int j2 = 0; j2 < 2; j2++)
                #pragma unroll
                for (int fc = 0; fc < 4; fc++)
                    #pragma unroll
                    for (int kg = 0; kg < 2; kg++)
                        acc[q * 2 + j2][fc] = __builtin_amdgcn_mfma_f32_16x16x32_bf16(
                            af[j2][kg], bfr[fc][kg], acc[q * 2 + j2][fc], 0, 0, 0);
            __builtin_amdgcn_s_setprio(0);

            if (p == 3) {
                if (2 * u + 2 < T) asm volatile("s_waitcnt vmcnt(4)" ::: "memory");
                else               asm volatile("s_waitcnt vmcnt(0)" ::: "memory");
            }
            if (p == 7 && (u + 1) < (T >> 1)) {
                asm volatile("s_waitcnt vmcnt(4)" ::: "memory");
            }

            __builtin_amdgcn_s_barrier();
        }
    }

    const int crow = (ln >> 4) * 4, ccol = ln & 15;

    if ((z >> 3) == 2) {
        // V -> Vt (b,h,e,s)
        ushort_t* O = (ushort_t*)Cout2;
        const int h = z & 7;
        #pragma unroll
        for (int fr = 0; fr < 8; fr++) {
            #pragma unroll
            for (int fc = 0; fc < 4; fc++) {
                int gm0 = m0 + wm * 128 + fr * 16 + crow;
                int gn  = n0 + wn * 64 + fc * 16 + ccol;
                int b = gm0 >> 10, s = gm0 & 1023;
                us4 pk = { f2bf(acc[fr][fc][0]), f2bf(acc[fr][fc][1]),
                           f2bf(acc[fr][fc][2]), f2bf(acc[fr][fc][3]) };
                *(us4*)(O + ((size_t)(b * Hh + h) * Ee + gn) * Ss + s) = pk;
            }
        }
    } else {
        ushort_t* scr = SMEM + wv * 4608;                  // 64 x 72 ushorts per wave
        for (int pass = 0; pass < 2; ++pass) {
            #pragma unroll
            for (int fr2 = 0; fr2 < 4; fr2++) {
                int fr = pass * 4 + fr2;
                #pragma unroll
                for (int fc = 0; fc < 4; fc++)
                    #pragma unroll
                    for (int i = 0; i < 4; i++)
                        scr[(fr2 * 16 + crow + i) * 72 + fc * 16 + ccol] = f2bf(acc[fr][fc][i]);
            }
            #pragma unroll
            for (int rr = 0; rr < 8; ++rr) {
                int r = rr * 8 + (ln >> 3);
                int c = (ln & 7) * 8;
                short8 v = *(const short8*)&scr[r * 72 + c];
                int gm = m0 + wm * 128 + pass * 64 + r;
                int gn = n0 + wn * 64 + c;
                ushort_t* O = (ushort_t*)Cout;
                int mat = z >> 3, h = z & 7;
                int b = gm >> 10, s = gm & 1023;
                size_t addr = (size_t)mat * 16777216 + ((size_t)(b * Hh + h) * Ss + s) * Ee + gn;
                *(short8*)&O[addr] = v;
            }
        }
    }
}

// ---------------- fused scores+PV (flash-style, no attn materialization) ----------
// Block = (b,h, 64-row q-tile). Q in registers (16 short8/lane). Loop 32 kv-tiles
// of 32: {stage K-tile 32x512 + Vt-slab 512x32 (dbuf) early} -> QK^T (16 MFMA) ->
// exp(-g*max(q2+k2-2s,0)) -> P to LDS -> lgkm-barrier (vmcnt stays in flight) ->
// PV (16 MFMA into O-acc) -> vmcnt(0)+barrier (loads had whole iter to land).
// LDS: K dbuf 2x32KB @0 | V dbuf 2x32KB @32768u | P 4KB @65536u  (132 KB total).
// Swizzles: K chunk c^(r&7), V/P chunk c^(row&3) -- proven-engine pattern.
__global__ __launch_bounds__(512, 1)
void g_fused(const ushort_t* __restrict__ Qb, const ushort_t* __restrict__ Kb,
             const ushort_t* __restrict__ Vt, ushort_t* __restrict__ Ob,
             const float* __restrict__ q2, const float* __restrict__ k2,
             const float* __restrict__ gamma)
{
    __shared__ __align__(16) ushort_t SMEM[67584];   // 132 KB

    const int t  = threadIdx.x;
    const int wv = t >> 6, ln = t & 63;
    const int lrow = ln & 15, lkg = ln >> 4;         // lkg = k-group 0..3
    const int crow = lkg * 4, ccol = lrow;

    // slice-major XCD mapping: per XCD 4 bh sequentially -> ~2 bh (4 MB) live per L2
    const int L = blockIdx.x + gridDim.x * blockIdx.y;   // grid (16, 32)
    const int xcd = L & 7;
    const int j = L >> 3;
    const int bh = xcd + 8 * (j >> 4);
    const int qx = j & 15;
    const int q0 = qx * 64;
    const int b = bh >> 3, h = bh & 7;

    // QK^T roles: wq in 0..3 (q-group), wkv in 0..1 (kv-group)
    const int wq = wv >> 1, wkv = wv & 1;
    // PV roles: wm2 in 0..1 (q-half), wn2 in 0..3 (e-group of 128)
    const int wm2 = wv >> 2, wn2 = wv & 3;

    // Q-tile in registers: 16 short8/lane (rows wq*16+lrow, k = ks*32 + lkg*8)
    const ushort_t* Qrow = Qb + ((size_t)bh * Ss + q0 + wq * 16 + lrow) * Ee + lkg * 8;
    short8 qf[16];
    #pragma unroll
    for (int ks = 0; ks < 16; ks++) qf[ks] = *(const short8*)(Qrow + ks * 32);

    // q2 for this lane's 4 S-rows (fixed all iters); gamma
    const float g = gamma[h];
    float q2v[4];
    #pragma unroll
    for (int i = 0; i < 4; i++) q2v[i] = q2[(size_t)bh * Ss + q0 + wq * 16 + crow + i];
    const float* k2b = k2 + (size_t)bh * Ss;

    const ushort_t* Kbase = Kb + (size_t)bh * Ss * Ee;
    const ushort_t* Vbase = Vt + (size_t)bh * Ee * Ss;

    auto STAGE_K = [&](int t0, int buf) {   // 32 rows x 1KB; 4 calls/wave (1 row each)
        #pragma unroll
        for (int c = 0; c < 4; c++) {
            int r = wv * 4 + c;
            gload_lds16(Kbase + (size_t)(t0 + r) * Ee + ((ln ^ (r & 7)) * 8),
                        &SMEM[buf * 16384 + r * 512 + ln * 8]);
        }
    };
    auto STAGE_V = [&](int t0, int buf) {   // 512 rows x 64B; 4 calls/wave (16 rows each)
        #pragma unroll
        for (int c = 0; c < 4; c++) {
            int idx = wv * 4 + c;
            int e = idx * 16 + (ln >> 2);
            gload_lds16(Vbase + (size_t)e * Ss + t0 + (((ln & 3) ^ (e & 3)) * 8),
                        &SMEM[32768 + buf * 16384 + idx * 512 + ln * 8]);
        }
    };

    f32x4 oacc[2][8];
    #pragma unroll
    for (int mi = 0; mi < 2; mi++)
        #pragma unroll
        for (int fe = 0; fe < 8; fe++) oacc[mi][fe] = (f32x4){0.f, 0.f, 0.f, 0.f};

    STAGE_K(0, 0); STAGE_V(0, 0);
    __syncthreads();

    int cur = 0;
    for (int kt = 0; kt < 32; ++kt) {
        if (kt + 1 < 32) { STAGE_K((kt + 1) * 32, cur ^ 1); STAGE_V((kt + 1) * 32, cur ^ 1); }

        // QK^T: per-wave 16x16 S-tile, K=512
        f32x4 s = (f32x4){0.f, 0.f, 0.f, 0.f};
        const int kr = wkv * 16 + lrow;
        #pragma unroll
        for (int ks = 0; ks < 16; ks++) {
            int c = ks * 4 + lkg;
            short8 bf = *(const short8*)(&SMEM[cur * 16384 + kr * 512 + ((c ^ (kr & 7)) * 8)]);
            s = __builtin_amdgcn_mfma_f32_16x16x32_bf16(qf[ks], bf, s, 0, 0, 0);
        }

        // fused RBF epilogue -> P (bf16) to LDS
        float k2c = k2b[kt * 32 + wkv * 16 + ccol];
        #pragma unroll
        for (int i = 0; i < 4; i++) {
            float d2 = fmaxf(q2v[i] + k2c - 2.0f * s[i], 0.0f);
            float pv = __expf(-g * d2);
            int pr = wq * 16 + crow + i;
            int pc = wkv * 16 + ccol;
            int chunk = pc >> 3;
            SMEM[65536 + pr * 32 + ((chunk ^ (pr & 3)) * 8) + (pc & 7)] = f2bf(pv);
        }

        asm volatile("s_waitcnt lgkmcnt(0)" ::: "memory");   // P visible; vmcnt stays in flight
        __builtin_amdgcn_s_barrier();
        __builtin_amdgcn_sched_barrier(0);

        // PV: O[64x512] += P[64x32] * V; wave: 32q x 128e, K=32
        short8 vb[8];
        #pragma unroll
        for (int fe = 0; fe < 8; fe++) {
            int er = wn2 * 128 + fe * 16 + lrow;
            vb[fe] = *(const short8*)(&SMEM[32768 + cur * 16384 + er * 32 + ((lkg ^ (er & 3)) * 8)]);
        }
        #pragma unroll
        for (int mi = 0; mi < 2; mi++) {
            int pr = wm2 * 32 + mi * 16 + lrow;
            short8 pa = *(const short8*)(&SMEM[65536 + pr * 32 + ((lkg ^ (pr & 3)) * 8)]);
            #pragma unroll
            for (int fe = 0; fe < 8; fe++)
                oacc[mi][fe] = __builtin_amdgcn_mfma_f32_16x16x32_bf16(pa, vb[fe], oacc[mi][fe], 0, 0, 0);
        }

        asm volatile("s_waitcnt vmcnt(0)" ::: "memory");     // next tile landed (issued a full iter ago)
        __builtin_amdgcn_s_barrier();                        // all reads done; bufs/P safe to overwrite
        __builtin_amdgcn_sched_barrier(0);
        cur ^= 1;
    }

    // epilogue: O-acc -> Ob ((b,s),(h,e)) via per-wave LDS staging, 256B row stores
    ushort_t* scr = SMEM + wv * 4352;   // 32 rows x 136 ushorts per wave
    #pragma unroll
    for (int mi = 0; mi < 2; mi++)
        #pragma unroll
        for (int fe = 0; fe < 8; fe++)
            #pragma unroll
            for (int i = 0; i < 4; i++)
                scr[(mi * 16 + crow + i) * 136 + fe * 16 + ccol] = f2bf(oacc[mi][fe][i]);
    #pragma unroll
    for (int rr = 0; rr < 8; rr++) {
        int r = rr * 4 + lkg;            // 0..31
        int c = lrow * 8;                // ushort col 0..120
        short8 v = *(const short8*)&scr[r * 136 + c];
        size_t addr = ((size_t)(b * Ss + q0 + wm2 * 32 + r)) * (Hh * Ee) + (size_t)h * Ee + wn2 * 128 + c;
        *(short8*)&Ob[addr] = v;
    }
}

// ---------------- final GEMM: 128x128 deep-K engine, split-K x2 ----------------
__global__ __launch_bounds__(256)
void g_final(const ushort_t* __restrict__ A, int lda,
             const ushort_t* __restrict__ Bm, int ldb,
             float* __restrict__ Cout, int K)
{
    __shared__ __align__(16) ushort_t SMEM[16384];  // 32 KB

    const int t  = threadIdx.x;
    const int wv = t >> 6, ln = t & 63;
    const int wr = wv >> 1, wc = wv & 1;

    const int gx = gridDim.x, gy = gridDim.y;
    const int nwg = gx * gy * gridDim.z;
    const int L = blockIdx.x + gx * (blockIdx.y + gy * blockIdx.z);
    const int wid = (L & 7) * (nwg >> 3) + (L >> 3);
    const int bx = wid % gx;
    const int tmp = wid / gx;
    const int by = tmp % gy;
    const int z  = tmp / gy;

    const int m0 = by * 128, n0 = bx * 128;
    const ushort_t* Ab = A  + (size_t)z * 2048;
    const ushort_t* Bb = Bm + (size_t)z * 2048;

    f32x4 acc[4][4];
    #pragma unroll
    for (int i = 0; i < 4; i++)
        #pragma unroll
        for (int j = 0; j < 4; j++) acc[i][j] = (f32x4){0.f, 0.f, 0.f, 0.f};

    const int rstage = t >> 2;
    const int cchunk = t & 3;

    auto STAGE = [&](int ti, int buf) {
        const int k0 = ti << 5;
        #pragma unroll
        for (int i = 0; i < 2; i++) {
            gload_lds16(Ab + (size_t)(m0 + i * 64 + rstage) * lda + k0 + cchunk * 8,
                        (char*)SMEM + buf * 8192 + i * 4096 + wv * 1024);
            gload_lds16(Bb + (size_t)(n0 + i * 64 + rstage) * ldb + k0 + cchunk * 8,
                        (char*)SMEM + 16384 + buf * 8192 + i * 4096 + wv * 1024);
        }
    };

    const int nt = K >> 5;
    STAGE(0, 0);
    __syncthreads();

    int cur = 0;
    const int lrow = ln & 15, kg = ln >> 4;
    for (int ti = 0; ti < nt; ++ti) {
        if (ti + 1 < nt) STAGE(ti + 1, cur ^ 1);

        short8 af[4], bfr[4];
        #pragma unroll
        for (int fr = 0; fr < 4; fr++)
            af[fr] = *(const short8*)(&SMEM[cur * 4096 + (wr * 64 + fr * 16 + lrow) * 32 + kg * 8]);
        #pragma unroll
        for (int fc = 0; fc < 4; fc++)
            bfr[fc] = *(const short8*)(&SMEM[8192 + cur * 4096 + (wc * 64 + fc * 16 + lrow) * 32 + kg * 8]);
        #pragma unroll
        for (int fr = 0; fr < 4; fr++)
            #pragma unroll
            for (int fc = 0; fc < 4; fc++)
                acc[fr][fc] = __builtin_amdgcn_mfma_f32_16x16x32_bf16(af[fr], bfr[fc], acc[fr][fc], 0, 0, 0);

        __syncthreads();
        cur ^= 1;
    }

    const int crow = (ln >> 4) * 4, ccol = ln & 15;
    float* O = Cout + (size_t)z * 4096 * 512;
    float* fscr = (float*)SMEM + wv * 1088;            // 16 x 68 f32 per wave
    #pragma unroll
    for (int pass = 0; pass < 4; ++pass) {
        #pragma unroll
        for (int fc = 0; fc < 4; fc++)
            #pragma unroll
            for (int i = 0; i < 4; i++)
                fscr[(crow + i) * 68 + fc * 16 + ccol] = acc[pass][fc][i];
        #pragma unroll
        for (int rr = 0; rr < 4; ++rr) {
            int r = rr * 4 + (ln >> 4);
            int c = (ln & 15) * 4;
            f32x4 v = *(const f32x4*)&fscr[r * 68 + c];
            int gm = m0 + wr * 64 + pass * 16 + r;
            int gn = n0 + wc * 64 + c;
            *(f32x4*)&O[(size_t)gm * 512 + gn] = v;
        }
    }
}

// ---------------- host ----------------

extern "C" void kernel_launch(void* const* d_in, const int* in_sizes, int n_in,
                              void* d_out, int out_size, void* d_ws, size_t ws_size,
                              hipStream_t stream)
{
    const float* x     = (const float*)d_in[0];
    const float* Wq    = (const float*)d_in[3];
    const float* Wk    = (const float*)d_in[4];
    const float* Wv    = (const float*)d_in[5];
    const float* Wo    = (const float*)d_in[6];
    const float* gamma = (const float*)d_in[7];

    char* ws = (char*)d_ws;
    size_t off = 0;
    auto alloc = [&](size_t bytes) -> void* {
        void* p = ws + off;
        off += (bytes + 255) & ~(size_t)255;
        return p;
    };
    ushort_t* xb    = (ushort_t*)alloc(4096ull * 512 * 2);        // x bf16
    ushort_t* Wt    = (ushort_t*)alloc(24ull * 512 * 512 * 2);    // WqT|WkT|WvT contiguous
    ushort_t* WoB   = (ushort_t*)alloc(512ull * 4096 * 2);        // (e_out, h*e_in)
    ushort_t* Qb    = (ushort_t*)alloc(4ull * 8 * 1024 * 512 * 2);// (b,h,s,e)
    ushort_t* Kb    = (ushort_t*)alloc(4ull * 8 * 1024 * 512 * 2);// contiguous after Qb
    ushort_t* Vt    = (ushort_t*)alloc(4ull * 8 * 512 * 1024 * 2);// (b,h,e,s)
    float*    q2    = (float*)alloc(32768ull * 4);
    float*    k2    = (float*)alloc(32768ull * 4);                // contiguous after q2
    ushort_t* Ob    = (ushort_t*)alloc(4096ull * 4096 * 2);       // ((b,s),(h,e))
    float*    fpart = (float*)Qb;  // 2 x 8 MB split-K partials (Qb dead after g_fused)
    (void)in_sizes; (void)n_in; (void)out_size; (void)ws_size;

    cvt_f32_bf16<<<2048, 256, 0, stream>>>((const float4*)x,  (us4*)xb,  524288);
    cvt_f32_bf16<<<2048, 256, 0, stream>>>((const float4*)Wo, (us4*)WoB, 524288);

    dim3 tb(32, 8);
    wtrans_all<<<dim3(16, 16, 24), tb, 0, stream>>>(Wq, Wk, Wv, Wt);

    // merged Q/K/V projections: M=4096, N=512, K=512; z = mat*8+h (24 slices)
    g_proj<<<dim3(2, 16, 24), 512, 0, stream>>>(xb, 512, Wt, 512, Qb, 512, Vt);

    // sum-of-squares over Q and K rows (Qb,Kb contiguous; q2,k2 contiguous)
    sumsq<<<16384, 256, 0, stream>>>(Qb, q2);

    // fused scores+PV: grid (16 q-tiles, 32 bh)
    g_fused<<<dim3(16, 32), 512, 0, stream>>>(Qb, Kb, Vt, Ob, q2, k2, gamma);

    // final: M=4096, N=512, K=4096 split into 2 K-slices of 2048 (deep-K engine)
    g_final<<<dim3(4, 32, 2), 256, 0, stream>>>(Ob, 4096, WoB, 4096, fpart, 2048);
    reduce2<<<2048, 256, 0, stream>>>((const f32x4*)fpart, (f32x4*)d_out, 524288);
}

// Round 15
// 213.167 us; speedup vs baseline: 1.2124x; 1.2124x over previous
//
#include <hip/hip_runtime.h>
#include <cstdint>
#include <cstring>

typedef unsigned short ushort_t;
typedef __attribute__((ext_vector_type(8))) short short8;
typedef __attribute__((ext_vector_type(4))) float f32x4;
typedef __attribute__((ext_vector_type(4))) unsigned short us4;

constexpr int Hh = 8;
constexpr int Ss = 1024;
constexpr int Ee = 512;

__device__ __forceinline__ ushort_t f2bf(float f) {
    uint32_t u; __builtin_memcpy(&u, &f, 4);
    u += 0x7fffu + ((u >> 16) & 1u);   // RNE
    return (ushort_t)(u >> 16);
}
__device__ __forceinline__ float bf2f(ushort_t h) {
    uint32_t u = ((uint32_t)h) << 16; float f; __builtin_memcpy(&f, &u, 4); return f;
}

__device__ __forceinline__ void gload_lds16(const ushort_t* g, void* lds) {
    __builtin_amdgcn_global_load_lds(
        (const __attribute__((address_space(1))) void*)g,
        (__attribute__((address_space(3))) void*)lds, 16, 0, 0);
}

// ---------------- small kernels ----------------

__global__ void cvt_f32_bf16(const float4* __restrict__ in, us4* __restrict__ out, int n4) {
    int i = blockIdx.x * blockDim.x + threadIdx.x;
    if (i < n4) {
        float4 v = in[i];
        us4 o = { f2bf(v.x), f2bf(v.y), f2bf(v.z), f2bf(v.w) };
        out[i] = o;
    }
}

// all three W (h,e,f) fp32 -> contiguous Wt (24 x 512 x 512) bf16; z = mat*8+h
__global__ void wtrans_all(const float* __restrict__ Wq, const float* __restrict__ Wk,
                           const float* __restrict__ Wv, ushort_t* __restrict__ Wt) {
    __shared__ float tile[32][33];
    int zz = blockIdx.z;
    int h = zz & 7, sel = zz >> 3;
    const float* W = (sel == 0 ? Wq : (sel == 1 ? Wk : Wv));
    int e0 = blockIdx.y * 32, f0 = blockIdx.x * 32;
    int tx = threadIdx.x, ty = threadIdx.y;
    #pragma unroll
    for (int i = 0; i < 4; i++) {
        int e = e0 + ty + i * 8;
        tile[ty + i * 8][tx] = W[((size_t)h * 512 + e) * 512 + f0 + tx];
    }
    __syncthreads();
    #pragma unroll
    for (int i = 0; i < 4; i++) {
        int f = f0 + ty + i * 8;
        Wt[((size_t)zz * 512 + f) * 512 + e0 + tx] = f2bf(tile[tx][ty + i * 8]);
    }
}

// row-wise sum of squares over 512 bf16 elems; one wave per row
__global__ void sumsq(const ushort_t* __restrict__ X, float* __restrict__ out) {
    int row = blockIdx.x * 4 + (threadIdx.x >> 6);
    int ln = threadIdx.x & 63;
    short8 v = *(const short8*)(X + (size_t)row * 512 + ln * 8);
    float s = 0.f;
    #pragma unroll
    for (int j = 0; j < 8; j++) {
        float f = bf2f((ushort_t)v[j]);
        s += f * f;
    }
    #pragma unroll
    for (int off = 32; off > 0; off >>= 1) s += __shfl_xor(s, off);
    if (ln == 0) out[row] = s;
}

// sum 2 fp32 partials -> out
__global__ void reduce2(const f32x4* __restrict__ p, f32x4* __restrict__ out, int n4) {
    int i = blockIdx.x * blockDim.x + threadIdx.x;
    if (i < n4) out[i] = p[i] + p[i + (size_t)n4];
}

// ---------------- 256x256 GEMM body (R10 engine, best measured) ----------------
// BK=64, 8 waves (2M x 4N), 512 threads, LDS 128 KB dbuf; 8-phase, counted vmcnt,
// T2 swizzle both-sides, setprio, hoisted staging bases, slice-major XCD swizzle.
// EPI 2: scores: exp(-gamma*max(q2+k2-2qk,0)) -> attn bf16; z = slice
// EPI 3: PV -> O bf16 ((b,s),(h,e)); z = slice
// EPI 5: merged QKV projection; z in [0,24): mat=z>>3 (0=Q,1=K,2=V), h=z&7.
//        B = Wt + z*512*512 (contiguous); Q/K -> Cout + mat*16Mi elems (b,h,s,f);
//        V -> Cout2 as Vt (b,h,f,s).
template<int EPI>
__device__ __forceinline__
void gemm256_body(const ushort_t* __restrict__ A, int lda,
                  const ushort_t* __restrict__ Bm, int ldb,
                  void* __restrict__ Cout, int K,
                  const float* __restrict__ q2, const float* __restrict__ k2,
                  const float* __restrict__ gamma, int bIdx,
                  void* __restrict__ Cout2)
{
    __shared__ __align__(16) ushort_t SMEM[65536];   // 128 KB: A[2][16384] | B[2][16384]

    const int t  = threadIdx.x;
    const int wv = t >> 6, ln = t & 63;
    const int wm = wv >> 2, wn = wv & 3;

    // slice-major XCD swizzle (bijective; gz % 8 == 0)
    const int gx = gridDim.x, gy = gridDim.y;
    const int gxy = gx * gy;
    const int L = blockIdx.x + gx * (blockIdx.y + gy * blockIdx.z);
    const int xcd = L & 7;
    const int j = L >> 3;
    const int z  = xcd + 8 * (j / gxy);
    const int rem = j % gxy;
    const int by = rem / gx;
    const int bx = rem % gx;

    const int m0 = by * 256, n0 = bx * 256;

    int bh = z;
    if constexpr (EPI == 2 || EPI == 3) bh = (bIdx < 0) ? z : (bIdx * Hh + z);

    const ushort_t* Ab = A;
    const ushort_t* Bb = Bm;
    if constexpr (EPI == 5) { Bb = Bm + (size_t)z * Ee * Ee; }
    if constexpr (EPI == 2) {
        Ab = A  + (size_t)bh * Ss * Ee;
        Bb = Bm + (size_t)bh * Ss * Ee;
    }
    if constexpr (EPI == 3) {
        Ab = A  + (size_t)z * Ss * Ss;
        Bb = Bm + (size_t)bh * Ee * Ss;
    }

    f32x4 acc[8][4];
    #pragma unroll
    for (int i = 0; i < 8; i++)
        #pragma unroll
        for (int j2 = 0; j2 < 4; j2++) acc[i][j2] = (f32x4){0.f, 0.f, 0.f, 0.f};

    // staging: idx 0..31 covers rows idx*8+srow; source chunk (ln&7)^(ln>>3)
    // (involution); linear LDS dest idx*512+ln*8 -> slot (R,c) holds chunk c^(R&7).
    const int srow = ln >> 3;
    const int schk = ((ln & 7) ^ srow) * 8;
    const ushort_t* sbase[4][2];
    int ldso[4][2];
    #pragma unroll
    for (int kind = 0; kind < 4; ++kind) {
        #pragma unroll
        for (int c = 0; c < 2; ++c) {
            const int idx = (kind & 1) * 16 + wv * 2 + c;
            const int rb = idx * 8 + srow;
            sbase[kind][c] = (kind < 2)
                ? Ab + (size_t)(m0 + rb) * lda + schk
                : Bb + (size_t)(n0 + rb) * ldb + schk;
            ldso[kind][c] = (kind < 2 ? 0 : 32768) + idx * 512;
        }
    }
    auto STAGE_UNIT = [&](int tile, int kind) {
        const int k0 = tile << 6;
        const int par = (tile & 1) * 16384;
        #pragma unroll
        for (int c = 0; c < 2; ++c)
            gload_lds16(sbase[kind][c] + k0, &SMEM[ldso[kind][c] + par]);
    };

    const int T = K >> 6;

    #pragma unroll
    for (int kk = 0; kk < 4; ++kk) STAGE_UNIT(0, kk);
    #pragma unroll
    for (int kk = 0; kk < 4; ++kk) STAGE_UNIT(1, kk);
    asm volatile("s_waitcnt vmcnt(8)" ::: "memory");
    __builtin_amdgcn_s_barrier();

    const int lrow = ln & 15, lkg = ln >> 4;
    const int swz = lrow & 7;

    for (int u = 0; u < (T >> 1); ++u) {
        short8 bfr[4][2];
        #pragma unroll
        for (int p = 0; p < 8; ++p) {
            const int d = p >> 2, q = p & 3;

            if (q == 0) {
                #pragma unroll
                for (int fc = 0; fc < 4; fc++)
                    #pragma unroll
                    for (int kg = 0; kg < 2; kg++)
                        bfr[fc][kg] = *(const short8*)(&SMEM[32768 + d * 16384 +
                                          (wn * 64 + fc * 16 + lrow) * 64 +
                                          (((kg * 4 + lkg) ^ swz) << 3)]);
            }
            short8 af[2][2];
            #pragma unroll
            for (int j2 = 0; j2 < 2; j2++)
                #pragma unroll
                for (int kg = 0; kg < 2; kg++)
                    af[j2][kg] = *(const short8*)(&SMEM[d * 16384 +
                                     (wm * 128 + (q * 2 + j2) * 16 + lrow) * 64 +
                                     (((kg * 4 + lkg) ^ swz) << 3)]);

            {
                int stile, skind;
                if      (p == 0) { stile = 2 * u + 1; skind = 0; }
                else if (p == 1) { stile = 2 * u + 1; skind = 1; }
                else if (p == 2) { stile = 2 * u + 2; skind = 2; }
                else if (p == 3) { stile = 2 * u + 2; skind = 3; }
                else if (p == 4) { stile = 2 * u + 2; skind = 0; }
                else if (p == 5) { stile = 2 * u + 2; skind = 1; }
                else if (p == 6) { stile = 2 * u + 3; skind = 2; }
                else             { stile = 2 * u + 3; skind = 3; }
                if (stile < T && !(u == 0 && stile == 1))
                    STAGE_UNIT(stile, skind);
            }

            __builtin_amdgcn_s_barrier();

            __builtin_amdgcn_s_setprio(1);
            #pragma unroll
            for (int j2 = 0; j2 < 2; j2++)
                #pragma unroll
                for (int fc = 0; fc < 4; fc++)
                    #pragma unroll
                    for (int kg = 0; kg < 2; kg++)
                        acc[q * 2 + j2][fc] = __builtin_amdgcn_mfma_f32_16x16x32_bf16(
                            af[j2][kg], bfr[fc][kg], acc[q * 2 + j2][fc], 0, 0, 0);
            __builtin_amdgcn_s_setprio(0);

            if (p == 3) {
                if (2 * u + 2 < T) asm volatile("s_waitcnt vmcnt(4)" ::: "memory");
                else               asm volatile("s_waitcnt vmcnt(0)" ::: "memory");
            }
            if (p == 7 && (u + 1) < (T >> 1)) {
                asm volatile("s_waitcnt vmcnt(4)" ::: "memory");
            }

            __builtin_amdgcn_s_barrier();
        }
    }
    // drained -> SMEM reusable as epilogue scratch

    const int crow = (ln >> 4) * 4, ccol = ln & 15;

    bool vtpath = false;
    if constexpr (EPI == 5) vtpath = ((z >> 3) == 2);

    if (vtpath) {
        // V -> Vt (b,h,e,s): stores along s are 4x128B segments -- direct.
        ushort_t* O = (ushort_t*)Cout2;
        const int h = z & 7;
        #pragma unroll
        for (int fr = 0; fr < 8; fr++) {
            #pragma unroll
            for (int fc = 0; fc < 4; fc++) {
                int gm0 = m0 + wm * 128 + fr * 16 + crow;
                int gn  = n0 + wn * 64 + fc * 16 + ccol;
                int b = gm0 >> 10, s = gm0 & 1023;
                us4 pk = { f2bf(acc[fr][fc][0]), f2bf(acc[fr][fc][1]),
                           f2bf(acc[fr][fc][2]), f2bf(acc[fr][fc][3]) };
                *(us4*)(O + ((size_t)(b * Hh + h) * Ee + gn) * Ss + s) = pk;
            }
        }
    } else {
        // bf16 row-contiguous outputs: 2 passes of 64 rows through padded
        // scratch, short8 row stores (8 rows x 128 B per wave-store).
        ushort_t* scr = SMEM + wv * 4608;                  // 64 x 72 ushorts per wave
        float g = 0.f; const float* q2b = nullptr; const float* k2b = nullptr;
        float k2v[4];
        if constexpr (EPI == 2) {
            g = gamma[z & 7];
            q2b = q2 + (size_t)bh * Ss;
            k2b = k2 + (size_t)bh * Ss;
            #pragma unroll
            for (int fc = 0; fc < 4; fc++) k2v[fc] = k2b[n0 + wn * 64 + fc * 16 + ccol];
        }
        for (int pass = 0; pass < 2; ++pass) {
            float q2p[4][4];
            if constexpr (EPI == 2) {
                #pragma unroll
                for (int fr2 = 0; fr2 < 4; fr2++)
                    #pragma unroll
                    for (int i = 0; i < 4; i++)
                        q2p[fr2][i] = q2b[m0 + wm * 128 + pass * 64 + fr2 * 16 + crow + i];
            }
            #pragma unroll
            for (int fr2 = 0; fr2 < 4; fr2++) {
                int fr = pass * 4 + fr2;
                #pragma unroll
                for (int fc = 0; fc < 4; fc++) {
                    #pragma unroll
                    for (int i = 0; i < 4; i++) {
                        float v = acc[fr][fc][i];
                        if constexpr (EPI == 2) {
                            float d2 = fmaxf(q2p[fr2][i] + k2v[fc] - 2.0f * v, 0.0f);
                            v = __expf(-g * d2);
                        }
                        scr[(fr2 * 16 + crow + i) * 72 + fc * 16 + ccol] = f2bf(v);
                    }
                }
            }
            #pragma unroll
            for (int rr = 0; rr < 8; ++rr) {
                int r = rr * 8 + (ln >> 3);
                int c = (ln & 7) * 8;
                short8 v = *(const short8*)&scr[r * 72 + c];
                int gm = m0 + wm * 128 + pass * 64 + r;
                int gn = n0 + wn * 64 + c;
                ushort_t* O = (ushort_t*)Cout;
                size_t addr;
                if constexpr (EPI == 5) {
                    int mat = z >> 3, h = z & 7;
                    int b = gm >> 10, s = gm & 1023;
                    addr = (size_t)mat * 16777216 + ((size_t)(b * Hh + h) * Ss + s) * Ee + gn;
                } else if constexpr (EPI == 2) {
                    addr = ((size_t)z * Ss + gm) * Ss + gn;
                } else {
                    int bo = (bIdx < 0) ? (z >> 3) : bIdx;
                    int hh = (bIdx < 0) ? (z & 7) : z;
                    addr = ((size_t)(bo * Ss + gm)) * (Hh * Ee) + (size_t)hh * Ee + gn;
                }
                *(short8*)&O[addr] = v;
            }
        }
    }
}

// distinct kernel names for per-dispatch profiling
__global__ __launch_bounds__(512, 1)
void g_proj(const ushort_t* A, int lda, const ushort_t* Bm, int ldb, void* C, int K,
            const float* q2, const float* k2, const float* gamma, int bIdx, void* C2)
{ gemm256_body<5>(A, lda, Bm, ldb, C, K, q2, k2, gamma, bIdx, C2); }

__global__ __launch_bounds__(512, 1)
void g_scores(const ushort_t* A, int lda, const ushort_t* Bm, int ldb, void* C, int K,
              const float* q2, const float* k2, const float* gamma, int bIdx, void* C2)
{ gemm256_body<2>(A, lda, Bm, ldb, C, K, q2, k2, gamma, bIdx, C2); }

__global__ __launch_bounds__(512, 1)
void g_pv(const ushort_t* A, int lda, const ushort_t* Bm, int ldb, void* C, int K,
          const float* q2, const float* k2, const float* gamma, int bIdx, void* C2)
{ gemm256_body<3>(A, lda, Bm, ldb, C, K, q2, k2, gamma, bIdx, C2); }

// ---------------- final GEMM: 128x128 deep-K engine (R12-verified), split-K x2 ----
__global__ __launch_bounds__(256)
void g_final(const ushort_t* __restrict__ A, int lda,
             const ushort_t* __restrict__ Bm, int ldb,
             float* __restrict__ Cout, int K)
{
    __shared__ __align__(16) ushort_t SMEM[16384];  // 32 KB

    const int t  = threadIdx.x;
    const int wv = t >> 6, ln = t & 63;
    const int wr = wv >> 1, wc = wv & 1;

    const int gx = gridDim.x, gy = gridDim.y;
    const int nwg = gx * gy * gridDim.z;
    const int L = blockIdx.x + gx * (blockIdx.y + gy * blockIdx.z);
    const int wid = (L & 7) * (nwg >> 3) + (L >> 3);
    const int bx = wid % gx;
    const int tmp = wid / gx;
    const int by = tmp % gy;
    const int z  = tmp / gy;

    const int m0 = by * 128, n0 = bx * 128;
    const ushort_t* Ab = A  + (size_t)z * 2048;
    const ushort_t* Bb = Bm + (size_t)z * 2048;

    f32x4 acc[4][4];
    #pragma unroll
    for (int i = 0; i < 4; i++)
        #pragma unroll
        for (int j = 0; j < 4; j++) acc[i][j] = (f32x4){0.f, 0.f, 0.f, 0.f};

    const int rstage = t >> 2;
    const int cchunk = t & 3;

    auto STAGE = [&](int ti, int buf) {
        const int k0 = ti << 5;
        #pragma unroll
        for (int i = 0; i < 2; i++) {
            gload_lds16(Ab + (size_t)(m0 + i * 64 + rstage) * lda + k0 + cchunk * 8,
                        (char*)SMEM + buf * 8192 + i * 4096 + wv * 1024);
            gload_lds16(Bb + (size_t)(n0 + i * 64 + rstage) * ldb + k0 + cchunk * 8,
                        (char*)SMEM + 16384 + buf * 8192 + i * 4096 + wv * 1024);
        }
    };

    const int nt = K >> 5;
    STAGE(0, 0);
    __syncthreads();

    int cur = 0;
    const int lrow = ln & 15, kg = ln >> 4;
    for (int ti = 0; ti < nt; ++ti) {
        if (ti + 1 < nt) STAGE(ti + 1, cur ^ 1);

        short8 af[4], bfr[4];
        #pragma unroll
        for (int fr = 0; fr < 4; fr++)
            af[fr] = *(const short8*)(&SMEM[cur * 4096 + (wr * 64 + fr * 16 + lrow) * 32 + kg * 8]);
        #pragma unroll
        for (int fc = 0; fc < 4; fc++)
            bfr[fc] = *(const short8*)(&SMEM[8192 + cur * 4096 + (wc * 64 + fc * 16 + lrow) * 32 + kg * 8]);
        #pragma unroll
        for (int fr = 0; fr < 4; fr++)
            #pragma unroll
            for (int fc = 0; fc < 4; fc++)
                acc[fr][fc] = __builtin_amdgcn_mfma_f32_16x16x32_bf16(af[fr], bfr[fc], acc[fr][fc], 0, 0, 0);

        __syncthreads();
        cur ^= 1;
    }

    const int crow = (ln >> 4) * 4, ccol = ln & 15;
    float* O = Cout + (size_t)z * 4096 * 512;
    float* fscr = (float*)SMEM + wv * 1088;            // 16 x 68 f32 per wave
    #pragma unroll
    for (int pass = 0; pass < 4; ++pass) {
        #pragma unroll
        for (int fc = 0; fc < 4; fc++)
            #pragma unroll
            for (int i = 0; i < 4; i++)
                fscr[(crow + i) * 68 + fc * 16 + ccol] = acc[pass][fc][i];
        #pragma unroll
        for (int rr = 0; rr < 4; ++rr) {
            int r = rr * 4 + (ln >> 4);
            int c = (ln & 15) * 4;
            f32x4 v = *(const f32x4*)&fscr[r * 68 + c];
            int gm = m0 + wr * 64 + pass * 16 + r;
            int gn = n0 + wc * 64 + c;
            *(f32x4*)&O[(size_t)gm * 512 + gn] = v;
        }
    }
}

// ---------------- host ----------------

extern "C" void kernel_launch(void* const* d_in, const int* in_sizes, int n_in,
                              void* d_out, int out_size, void* d_ws, size_t ws_size,
                              hipStream_t stream)
{
    const float* x     = (const float*)d_in[0];
    const float* Wq    = (const float*)d_in[3];
    const float* Wk    = (const float*)d_in[4];
    const float* Wv    = (const float*)d_in[5];
    const float* Wo    = (const float*)d_in[6];
    const float* gamma = (const float*)d_in[7];

    char* ws = (char*)d_ws;
    size_t off = 0;
    auto alloc = [&](size_t bytes) -> void* {
        void* p = ws + off;
        off += (bytes + 255) & ~(size_t)255;
        return p;
    };
    ushort_t* xb    = (ushort_t*)alloc(4096ull * 512 * 2);        // x bf16
    ushort_t* Wt    = (ushort_t*)alloc(24ull * 512 * 512 * 2);    // WqT|WkT|WvT contiguous
    ushort_t* WoB   = (ushort_t*)alloc(512ull * 4096 * 2);        // (e_out, h*e_in)
    ushort_t* Qb    = (ushort_t*)alloc(4ull * 8 * 1024 * 512 * 2);// (b,h,s,e)
    ushort_t* Kb    = (ushort_t*)alloc(4ull * 8 * 1024 * 512 * 2);// contiguous after Qb
    ushort_t* Vt    = (ushort_t*)alloc(4ull * 8 * 512 * 1024 * 2);// (b,h,e,s)
    float*    q2    = (float*)alloc(32768ull * 4);
    float*    k2    = (float*)alloc(32768ull * 4);                // contiguous after q2

    size_t off_common = off;
    size_t need_merged = off_common + 64ull * 1024 * 1024;
    bool merged = (ws_size >= need_merged);

    ushort_t* attn;
    ushort_t* Ob;
    float* fpart;
    if (merged) {
        attn = (ushort_t*)alloc(32ull * 1024 * 1024 * 2);  // (b*h, s, t)
        Ob   = Qb;                                         // alias (dead after scores)
        fpart = (float*)attn;                              // alias (dead after PV), 16 MB used
    } else {
        attn = (ushort_t*)alloc(8ull * 1024 * 1024 * 2);   // (h, s, t) per batch
        Ob   = (ushort_t*)alloc(4096ull * 4096 * 2);
        fpart = (float*)Qb;                                // 16 MB needed < Qb's 32 MB
    }
    (void)in_sizes; (void)n_in; (void)out_size;

    cvt_f32_bf16<<<2048, 256, 0, stream>>>((const float4*)x,  (us4*)xb,  524288);
    cvt_f32_bf16<<<2048, 256, 0, stream>>>((const float4*)Wo, (us4*)WoB, 524288);

    dim3 tb(32, 8);
    wtrans_all<<<dim3(16, 16, 24), tb, 0, stream>>>(Wq, Wk, Wv, Wt);

    // merged Q/K/V projections: M=4096, N=512, K=512; z = mat*8+h (24 slices)
    g_proj<<<dim3(2, 16, 24), 512, 0, stream>>>(xb, 512, Wt, 512, Qb, 512,
                                                nullptr, nullptr, nullptr, 0, Vt);

    // sum-of-squares over Q and K rows (Qb,Kb contiguous; q2,k2 contiguous)
    sumsq<<<16384, 256, 0, stream>>>(Qb, q2);

    if (merged) {
        g_scores<<<dim3(4, 4, 32), 512, 0, stream>>>(Qb, 512, Kb, 512, attn, 512, q2, k2, gamma, -1, nullptr);
        g_pv<<<dim3(2, 4, 32), 512, 0, stream>>>(attn, 1024, Vt, 1024, Ob, 1024, nullptr, nullptr, nullptr, -1, nullptr);
    } else {
        for (int b = 0; b < 4; b++) {
            g_scores<<<dim3(4, 4, 8), 512, 0, stream>>>(Qb, 512, Kb, 512, attn, 512, q2, k2, gamma, b, nullptr);
            g_pv<<<dim3(2, 4, 8), 512, 0, stream>>>(attn, 1024, Vt, 1024, Ob, 1024, nullptr, nullptr, nullptr, b, nullptr);
        }
    }

    // final: M=4096, N=512, K=4096 split into 2 K-slices of 2048 (deep-K engine)
    g_final<<<dim3(4, 32, 2), 256, 0, stream>>>(Ob, 4096, WoB, 4096, fpart, 2048);
    reduce2<<<2048, 256, 0, stream>>>((const f32x4*)fpart, (f32x4*)d_out, 524288);
}